// Round 8
// baseline (244.564 us; speedup 1.0000x reference)
//
#include <hip/hip_runtime.h>

// Spiking basal ganglia: T=512 serial LIF steps, B=256 circuits.
// R13: FAT BLOCKS for DRAM row locality. Retraction: R9/R11's "L3-warm ==
// cold" rows had FETCH_SIZE=NaN (second rocprof pass doesn't collect it) --
// the latency-bound conclusion was a counter misread. Real picture: every
// dispatch fetches ~72MB at ~950 GB/s and dur == FETCH/BW. The kernel is
// HBM-bound at ~20% efficiency because each wave touches 512B islands
// strided 128KB (one DRAM row activation per 512B). Fix: 64 blocks x 4
// adjacent circuits -> 2KB contiguous islands (4x row locality).
// 768 threads: waves 0..3 = consumers (one circuit each, full R9-verified
// recurrence), waves 4..11 = producers (wave p: array p&1, t-group p>>1;
// 2x dwordx4 per lane = 32B/lane; verbatim bit-exact I op sequence).
// S=16 steps/chunk, 32 chunks, double-buffered LDS (152KB total).

__global__ __launch_bounds__(768, 1) void bg_kernel(
    const float* __restrict__ x,      // [T,B,2]
    const float* __restrict__ dopa,   // [T,B]
    const float* __restrict__ Wd1,    // [128,2]
    const float* __restrict__ Wd2,    // [128,2]
    const float* __restrict__ nd1,    // [T,B,128]
    const float* __restrict__ nd2,    // [T,B,128]
    float* __restrict__ out)          // [T,B]
{
#pragma clang fp contract(off)
    constexpr int T = 512, B = 256;
    constexpr int S = 16;             // steps per chunk
    constexpr int NCH = T / S;        // 32 chunks

    // currents: [buf][step][circuit][pair][4] = {I1.x,I1.y,I2.x,I2.y}
    __shared__ float lds_I[2][S][4][64][4];   // 128 KB
    __shared__ float lds_x[T][4][2];          // 16 KB
    __shared__ float lds_d[T][4];             // 8 KB

    const int g    = blockIdx.x;      // circuit group: circuits 4g..4g+3
    const int tid  = threadIdx.x;
    const int wv   = tid >> 6;        // 0..3 consumers, 4..11 producers
    const int lane = tid & 63;
    const int bc0  = g * 4;

    // ---- prologue A: stage x/dopa for the 4 circuits (all 768 threads) ----
    for (int idx = tid; idx < T * 4; idx += 768) {
        const int t = idx >> 2, c = idx & 3;
        const float2 xv = *(const float2*)(x + (size_t)t * (B * 2) + (bc0 + c) * 2);
        lds_x[t][c][0] = xv.x;
        lds_x[t][c][1] = xv.y;
        lds_d[t][c]    = dopa[(size_t)t * B + bc0 + c];
    }
    __syncthreads();

    if (wv < 4) {
        // ============ CONSUMER wave c: full R9-verified recurrence =========
        const int c = wv;
        __syncthreads();   // matches producers' prologue stage(0) barrier

        float v1a = 0.0f, v1b = 0.0f;
        float v2a = 0.0f, v2b = 0.0f;
        float v_stn = 0.0f, v_gpi = 0.0f;
        float gate_reg = 0.0f;

        for (int i = 0; i < NCH; ++i) {
            const float (*buf)[4][64][4] = lds_I[i & 1];

#pragma unroll
            for (int s = 0; s < S; ++s) {
                const float4 I = *(const float4*)&buf[s][c][lane][0];

                // ---- bit-identical recurrence (R2..R12 verified) ----
                v1a = 0.8f * v1a + 0.2f * I.x;
                v1b = 0.8f * v1b + 0.2f * I.y;
                v2a = 0.8f * v2a + 0.2f * I.z;
                v2b = 0.8f * v2b + 0.2f * I.w;

                const bool s1a = v1a >= 0.5f, s1b = v1b >= 0.5f;
                const bool s2a = v2a >= 0.5f, s2b = v2b >= 0.5f;
                v1a = s1a ? 0.0f : v1a;
                v1b = s1b ? 0.0f : v1b;
                v2a = s2a ? 0.0f : v2a;
                v2b = s2b ? 0.0f : v2b;

                const int c1 = __popcll(__ballot(s1a)) + __popcll(__ballot(s1b));
                const int c2 = __popcll(__ballot(s2a)) + __popcll(__ballot(s2b));
                const float mean1 = (float)c1 * 0.0078125f;
                const float mean2 = (float)c2 * 0.0078125f;

                const float I_stn = mean2 * 0.5f;
                v_stn = 0.8f * v_stn + 0.2f * I_stn;
                const float s_stn = (v_stn >= 0.5f) ? 1.0f : 0.0f;
                v_stn = (v_stn >= 0.5f) ? 0.0f : v_stn;

                const float I_gpi = (0.4f + mean1 * -0.8f) + s_stn * 0.6f;
                v_gpi = 0.8f * v_gpi + 0.2f * I_gpi;
                const float s_gpi = (v_gpi >= 0.5f) ? 1.0f : 0.0f;
                v_gpi = (v_gpi >= 0.5f) ? 0.0f : v_gpi;

                const float gate = mean1 - s_gpi;   // wave-uniform

                // lane ((i&3)*16 + s) latches step i*16+s's gate
                const int latch = ((i & 3) << 4) | s;
                gate_reg = (lane == latch) ? gate : gate_reg;
            }

            if ((i & 3) == 3) {
                // store 64 gates for steps (i-3)*16 .. i*16+15
                const int t0 = (i - 3) * S;
                out[(size_t)(t0 + lane) * B + bc0 + c] = gate_reg;
            }

            __syncthreads();
        }
    } else {
        // ============ PRODUCERS (waves 4..11) ==============================
        const int p  = wv - 4;
        const int a  = p & 1;          // 0 -> nd1/Wd1, 1 -> nd2/Wd2
        const int tg = p >> 1;         // t-group: steps 4*tg .. 4*tg+3
        const float* na = a ? nd2 : nd1;
        const float* Wa = a ? Wd2 : Wd1;

        const int m  = lane & 15;      // pair window: pairs 4m..4m+3
        const int cL = lane >> 4;      // circuit owned by this lane

        // W rows for pairs q=4m+k: float4 at Wa + 4*q = Wa + 16m + 4k
        const float4 W0 = *(const float4*)(Wa + 16 * m + 0);
        const float4 W1 = *(const float4*)(Wa + 16 * m + 4);
        const float4 W2 = *(const float4*)(Wa + 16 * m + 8);
        const float4 W3 = *(const float4*)(Wa + 16 * m + 12);

        // stage(ch, bf): load 2KB/t contiguous (32B/lane), compute I halves
        // with the EXACT R2..R12 op sequence, write float2s into lds_I[bf].
        auto stage = [&](int ch, int bf) {
            float4 n0[4], n1[4];
#pragma unroll
            for (int j = 0; j < 4; ++j) {
                const int t = ch * S + tg * 4 + j;
                const float* src = na + ((size_t)t * B + bc0) * 128 + 8 * lane;
                n0[j] = *(const float4*)(src);
                n1[j] = *(const float4*)(src + 4);
            }
#pragma unroll
            for (int j = 0; j < 4; ++j) {
                const int s = tg * 4 + j;
                const int t = ch * S + s;
                const float xx  = lds_x[t][cL][0], xy = lds_x[t][cL][1];
                const float dop = lds_d[t][cL];
                // a==0: m1 = 1 + dop*0.5 ; a==1: m2 = 1 - dop*0.3 (verbatim)
                const float mod = a ? (1.0f - dop * 0.3f) : (1.0f + dop * 0.5f);

                // pair k=0: n0.xy with W0
                {
                    const float dA = __builtin_fmaf(xy, W0.y, xx * W0.x);
                    const float dB = __builtin_fmaf(xy, W0.w, xx * W0.z);
                    float2 o;
                    o.x = dA * mod + n0[j].x * 0.1f;
                    o.y = dB * mod + n0[j].y * 0.1f;
                    *(float2*)&lds_I[bf][s][cL][4 * m + 0][2 * a] = o;
                }
                // pair k=1: n0.zw with W1
                {
                    const float dA = __builtin_fmaf(xy, W1.y, xx * W1.x);
                    const float dB = __builtin_fmaf(xy, W1.w, xx * W1.z);
                    float2 o;
                    o.x = dA * mod + n0[j].z * 0.1f;
                    o.y = dB * mod + n0[j].w * 0.1f;
                    *(float2*)&lds_I[bf][s][cL][4 * m + 1][2 * a] = o;
                }
                // pair k=2: n1.xy with W2
                {
                    const float dA = __builtin_fmaf(xy, W2.y, xx * W2.x);
                    const float dB = __builtin_fmaf(xy, W2.w, xx * W2.z);
                    float2 o;
                    o.x = dA * mod + n1[j].x * 0.1f;
                    o.y = dB * mod + n1[j].y * 0.1f;
                    *(float2*)&lds_I[bf][s][cL][4 * m + 2][2 * a] = o;
                }
                // pair k=3: n1.zw with W3
                {
                    const float dA = __builtin_fmaf(xy, W3.y, xx * W3.x);
                    const float dB = __builtin_fmaf(xy, W3.w, xx * W3.z);
                    float2 o;
                    o.x = dA * mod + n1[j].z * 0.1f;
                    o.y = dB * mod + n1[j].w * 0.1f;
                    *(float2*)&lds_I[bf][s][cL][4 * m + 3][2 * a] = o;
                }
            }
        };

        // prologue B: chunk 0
        stage(0, 0);
        __syncthreads();

        for (int i = 0; i < NCH; ++i) {
            if (i + 1 < NCH) stage(i + 1, (i + 1) & 1);
            __syncthreads();
        }
    }
}

extern "C" void kernel_launch(void* const* d_in, const int* in_sizes, int n_in,
                              void* d_out, int out_size, void* d_ws, size_t ws_size,
                              hipStream_t stream) {
    const float* x    = (const float*)d_in[0];
    const float* dopa = (const float*)d_in[1];
    // d_in[2] = rpe — unused by the reference
    const float* Wd1  = (const float*)d_in[3];
    const float* Wd2  = (const float*)d_in[4];
    const float* nd1  = (const float*)d_in[5];
    const float* nd2  = (const float*)d_in[6];
    float* out = (float*)d_out;

    bg_kernel<<<dim3(64), dim3(768), 0, stream>>>(x, dopa, Wd1, Wd2, nd1, nd2, out);
}

// Round 10
// 186.760 us; speedup vs baseline: 1.3095x; 1.3095x over previous
//
#include <hip/hip_runtime.h>

// Spiking basal ganglia: T=512 serial LIF steps, B=256 circuits.
// R15 = R14's zero-handoff structure, FUSED (no d_ws, no 2nd launch).
// R14 post-mortem: it wrote 2MB to d_ws without checking ws_size -> likely
// OOB -> container death x2. Fix: counts are block-local (circuit b's
// stn/gpi tail needs only block b's counts), so they live in 8KB LDS and
// wave 0 runs the verbatim tail after one __syncthreads.
// Structure: 256 blocks (one circuit each) x 4 waves {d1,d2}x{half0,half1};
// lane owns ONE neuron; each wave streams its 256B half-row across T with a
// 2x16 ping-pong register pipeline (<=32 loads in flight, compiler-counted
// vmcnt) and ZERO barriers in the main loop -- a wave stalled on vmcnt never
// blocks the others; the CU memory pipe is never structurally drained.
// Bit-exact: membrane/I ops verbatim per neuron (contract off); counts are
// integer spike sums (partition-invariant vs the old ballot-pair scheme);
// stn/gpi tail verbatim. If this still runs ~1 TB/s, the 512B/128KB-stride
// pattern is the hardware ceiling (declare next round).

__global__ __launch_bounds__(256, 1) void bg_kernel(
    const float* __restrict__ x,      // [T,B,2]
    const float* __restrict__ dopa,   // [T,B]
    const float* __restrict__ Wd1,    // [128,2]
    const float* __restrict__ Wd2,    // [128,2]
    const float* __restrict__ nd1,    // [T,B,128]
    const float* __restrict__ nd2,    // [T,B,128]
    float* __restrict__ out)          // [T,B]
{
#pragma clang fp contract(off)
    constexpr int T = 512, B = 256;
    constexpr size_t TSTRIDE = (size_t)B * 128;   // noise t-stride (floats)

    __shared__ float lds_xm[T][4];    // {xx, xy, m1, m2} per step: 8 KB
    __shared__ uint4 cnt_lds[T];      // {d1h0, d1h1, d2h0, d2h1}: 8 KB

    const int b    = blockIdx.x;
    const int tid  = threadIdx.x;
    const int wv   = tid >> 6;        // 0..3: pop = wv>>1, half = wv&1
    const int lane = tid & 63;
    const int pop  = wv >> 1;
    const int half = wv & 1;

    // ---- prologue: stage {x, modulators} (all 256 threads), one barrier ----
    for (int t = tid; t < T; t += 256) {
        const float2 xv = *(const float2*)(x + (size_t)t * (B * 2) + b * 2);
        const float dop = dopa[(size_t)t * B + b];
        lds_xm[t][0] = xv.x;
        lds_xm[t][1] = xv.y;
        lds_xm[t][2] = 1.0f + dop * 0.5f;   // m1 (verbatim op)
        lds_xm[t][3] = 1.0f - dop * 0.3f;   // m2 (verbatim op)
    }
    __syncthreads();

    // ============ PHASE 1: all 4 waves, independent membrane scans =========
    // this lane owns neuron n = half*64 + lane of population pop, circuit b
    {
        const int n = half * 64 + lane;
        const float* nb = (pop ? nd2 : nd1) + (size_t)b * 128 + n;
        const float2 w  = *(const float2*)((pop ? Wd2 : Wd1) + 2 * n);

        float va = 0.0f;
        unsigned int cnt_reg = 0u;

        float arrA[16], arrB[16];

#define LOADG(dst, t0)                                                       \
        { _Pragma("unroll")                                                  \
          for (int k = 0; k < 16; ++k)                                       \
              dst[k] = nb[(size_t)((t0) + k) * TSTRIDE]; }

        // 16 steps: verbatim R2..R13 op sequence per neuron (contract off).
#define PROCG(src, t0, lbase)                                                \
        { _Pragma("unroll")                                                  \
          for (int k = 0; k < 16; ++k) {                                     \
              const float4 xm = *(const float4*)&lds_xm[(t0) + k][0];        \
              const float m   = pop ? xm.w : xm.z;                           \
              const float dot = __builtin_fmaf(xm.y, w.y, xm.x * w.x);       \
              const float I   = dot * m + src[k] * 0.1f;                     \
              va = 0.8f * va + 0.2f * I;                                     \
              const bool s = va >= 0.5f;                                     \
              va = s ? 0.0f : va;                                            \
              const int c = __popcll(__ballot(s));                           \
              cnt_reg = (lane == (lbase) + k) ? (unsigned int)c : cnt_reg;   \
          } }

        LOADG(arrA, 0)
        LOADG(arrB, 16)
        for (int gp = 0; gp < 16; ++gp) {
            const int t0 = gp * 32;
            const int lb = (gp & 1) * 32;      // == t0 & 63
            PROCG(arrA, t0, lb)
            if (gp < 15) LOADG(arrA, t0 + 32)
            PROCG(arrB, t0 + 16, lb + 16)
            if (gp < 15) LOADG(arrB, t0 + 48)
            if (gp & 1) {
                // lanes hold counts for steps (gp-1)*32 .. gp*32+31
                const int tw = (gp - 1) * 32;
                ((unsigned int*)&cnt_lds[tw + lane])[wv] = cnt_reg;
            }
        }
#undef LOADG
#undef PROCG
    }

    __syncthreads();

    // ============ PHASE 2 (wave 0 only): verbatim stn/gpi tail =============
    if (wv == 0) {
        float v_stn = 0.0f, v_gpi = 0.0f;

        for (int g = 0; g < 8; ++g) {
            const uint4 c4 = cnt_lds[g * 64 + lane];
            // lane j holds step g*64+j's counts; exact integer sums.
            const float mean1v = (float)(int)(c4.x + c4.y) * 0.0078125f;
            const float mean2v = (float)(int)(c4.z + c4.w) * 0.0078125f;

            float gate_reg = 0.0f;
#pragma unroll
            for (int j = 0; j < 64; ++j) {
                const float mean1 = __shfl(mean1v, j);
                const float mean2 = __shfl(mean2v, j);

                const float I_stn = mean2 * 0.5f;
                v_stn = 0.8f * v_stn + 0.2f * I_stn;
                const float s_stn = (v_stn >= 0.5f) ? 1.0f : 0.0f;
                v_stn = (v_stn >= 0.5f) ? 0.0f : v_stn;

                const float I_gpi = (0.4f + mean1 * -0.8f) + s_stn * 0.6f;
                v_gpi = 0.8f * v_gpi + 0.2f * I_gpi;
                const float s_gpi = (v_gpi >= 0.5f) ? 1.0f : 0.0f;
                v_gpi = (v_gpi >= 0.5f) ? 0.0f : v_gpi;

                const float gate = mean1 - s_gpi;   // wave-uniform

                gate_reg = (lane == j) ? gate : gate_reg;
            }
            // store 64 gates for steps g*64 .. g*64+63
            out[(size_t)(g * 64 + lane) * B + b] = gate_reg;
        }
    }
}

extern "C" void kernel_launch(void* const* d_in, const int* in_sizes, int n_in,
                              void* d_out, int out_size, void* d_ws, size_t ws_size,
                              hipStream_t stream) {
    const float* x    = (const float*)d_in[0];
    const float* dopa = (const float*)d_in[1];
    // d_in[2] = rpe — unused by the reference
    const float* Wd1  = (const float*)d_in[3];
    const float* Wd2  = (const float*)d_in[4];
    const float* nd1  = (const float*)d_in[5];
    const float* nd2  = (const float*)d_in[6];
    float* out = (float*)d_out;

    bg_kernel<<<dim3(256), dim3(256), 0, stream>>>(x, dopa, Wd1, Wd2, nd1, nd2, out);
}